// Round 6
// baseline (430.586 us; speedup 1.0000x reference)
//
#include <hip/hip_runtime.h>

#define NB 8
#define NN 10000
#define NE 160000
#define NNODES (NB*NN)          // 80000
#define NEDGE (NB*NE)           // 1280000
#define FIN 5
#define HID 128
#define EMB 256
#define ALAST 10
#define PROJ_IN (HID*5 + ALAST + 1)  // 651
#define NBLK ((NNODES+255)/256)      // 313
#define NSLICE 32
#define SLICE 313                    // ceil(10000/32)

// ---- CSR build via node-range ownership (no global atomics) ----
// block bi: graph = bi&7 (XCD-pinned), slice = bi>>3 owns nodes [lo,hi).
__global__ __launch_bounds__(256) void k_hist2(const int* __restrict__ edges,
                                               int* __restrict__ cnt) {
    int bi = blockIdx.x;
    int g = bi & 7, s = bi >> 3;
    int lo = s*SLICE;
    int hi = lo + SLICE; if (hi > NN) hi = NN;
    __shared__ int c[SLICE];
    for (int i = threadIdx.x; i < SLICE; i += 256) c[i] = 0;
    __syncthreads();
    const int4* dstp = (const int4*)(edges + (size_t)g*2*NE + NE);
    for (int i = threadIdx.x; i < NE/4; i += 256) {
        int4 d4 = dstp[i];
        if (d4.x >= lo && d4.x < hi) atomicAdd(&c[d4.x - lo], 1);
        if (d4.y >= lo && d4.y < hi) atomicAdd(&c[d4.y - lo], 1);
        if (d4.z >= lo && d4.z < hi) atomicAdd(&c[d4.z - lo], 1);
        if (d4.w >= lo && d4.w < hi) atomicAdd(&c[d4.w - lo], 1);
    }
    __syncthreads();
    for (int i = threadIdx.x; i < hi - lo; i += 256) cnt[g*NN + lo + i] = c[i];
}

__global__ void k_scan1(const int* __restrict__ cnt, int* __restrict__ rowStart,
                        int* __restrict__ bsum) {
    __shared__ int sh[256];
    int tid = threadIdx.x;
    int i = blockIdx.x*256 + tid;
    int v = (i < NNODES) ? cnt[i] : 0;
    sh[tid] = v;
    __syncthreads();
    for (int off = 1; off < 256; off <<= 1) {
        int t = (tid >= off) ? sh[tid - off] : 0;
        __syncthreads();
        sh[tid] += t;
        __syncthreads();
    }
    if (i < NNODES) rowStart[i] = sh[tid] - v;          // exclusive
    if (tid == 255) bsum[blockIdx.x] = sh[255];
}

__global__ void k_scan2(int* bsum) {
    __shared__ int sh[512];
    int tid = threadIdx.x;
    int v = (tid < NBLK) ? bsum[tid] : 0;
    sh[tid] = v;
    __syncthreads();
    for (int off = 1; off < 512; off <<= 1) {
        int t = (tid >= off) ? sh[tid - off] : 0;
        __syncthreads();
        sh[tid] += t;
        __syncthreads();
    }
    if (tid < NBLK) bsum[tid] = sh[tid] - v;            // exclusive
}

// add block offsets; compute dinv; prescale 5-dim features into SoA xs5
__global__ void k_scan3(int* __restrict__ rowStart, const int* __restrict__ bsum,
                        const int* __restrict__ cnt, float* __restrict__ dinv,
                        const float* __restrict__ x, float* __restrict__ xs5) {
    int i = blockIdx.x*256 + threadIdx.x;
    if (i < NNODES) {
        rowStart[i] = rowStart[i] + bsum[blockIdx.x];
        float dv = rsqrtf(1.0f + (float)cnt[i]);        // +1 = self loop
        dinv[i] = dv;
        #pragma unroll
        for (int f = 0; f < FIN; ++f)
            xs5[f*NNODES + i] = x[(size_t)i*FIN + f] * dv;
    }
    if (i == 0) rowStart[NNODES] = NEDGE;
}

// fill: LDS cursors seeded from rowStart; csrSrc writes stay in a ~20KB window
__global__ __launch_bounds__(256) void k_fill2(const int* __restrict__ edges,
                                               const int* __restrict__ rowStart,
                                               int* __restrict__ csrSrc) {
    int bi = blockIdx.x;
    int g = bi & 7, s = bi >> 3;
    int lo = s*SLICE;
    int hi = lo + SLICE; if (hi > NN) hi = NN;
    __shared__ int cur[SLICE];
    for (int i = threadIdx.x; i < hi - lo; i += 256) cur[i] = rowStart[g*NN + lo + i];
    __syncthreads();
    const int* base = edges + (size_t)g*2*NE;
    const int4* dstp = (const int4*)(base + NE);
    int gofs = g*NN;
    for (int i = threadIdx.x; i < NE/4; i += 256) {
        int4 d4 = dstp[i];
        int e0 = 4*i;
        if (d4.x >= lo && d4.x < hi) { int p = atomicAdd(&cur[d4.x-lo],1); csrSrc[p] = base[e0+0] + gofs; }
        if (d4.y >= lo && d4.y < hi) { int p = atomicAdd(&cur[d4.y-lo],1); csrSrc[p] = base[e0+1] + gofs; }
        if (d4.z >= lo && d4.z < hi) { int p = atomicAdd(&cur[d4.z-lo],1); csrSrc[p] = base[e0+2] + gofs; }
        if (d4.w >= lo && d4.w < hi) { int p = atomicAdd(&cur[d4.w-lo],1); csrSrc[p] = base[e0+3] + gofs; }
    }
}

// layer-1 aggregation on the 5 raw features (agg commutes with dense transform).
__global__ __launch_bounds__(256) void k_agg5(
        const int* __restrict__ rowStart, const int* __restrict__ csrSrc,
        const float* __restrict__ xs5, const float* __restrict__ dinv,
        float* __restrict__ ax) {
    int g = blockIdx.x;
    int graph = g & 7;
    int nl = (g >> 3)*256 + threadIdx.x;
    if (nl >= NN) return;
    int n = graph*NN + nl;
    float a0 = xs5[0*NNODES + n], a1 = xs5[1*NNODES + n], a2 = xs5[2*NNODES + n],
          a3 = xs5[3*NNODES + n], a4 = xs5[4*NNODES + n];
    int beg = rowStart[n], end = rowStart[n+1];
    for (int e = beg; e < end; ++e) {
        int s = csrSrc[e];
        a0 += xs5[0*NNODES + s];
        a1 += xs5[1*NNODES + s];
        a2 += xs5[2*NNODES + s];
        a3 += xs5[3*NNODES + s];
        a4 += xs5[4*NNODES + s];
    }
    float dv = dinv[n];
    ax[(size_t)n*FIN + 0] = a0*dv;
    ax[(size_t)n*FIN + 1] = a1*dv;
    ax[(size_t)n*FIN + 2] = a2*dv;
    ax[(size_t)n*FIN + 3] = a3*dv;
    ax[(size_t)n*FIN + 4] = a4*dv;
}

// Fused layer-1 dense + layer-2 dense:
// H1 = relu(ax @ W1^T + b1) computed on the fly per tile (never materialized),
// hs = (H1 @ W2^T) * dinv.  128x128 tile, 8x8 per thread.
#define KC 32
__global__ __launch_bounds__(256) void k_h12(
        const float* __restrict__ ax, const float* __restrict__ W1,
        const float* __restrict__ b1, const float* __restrict__ W2,
        const float* __restrict__ dinv, float* __restrict__ hs) {
    __shared__ float axs[FIN][128];
    __shared__ float w1s[FIN][128];
    __shared__ float b1s[128];
    __shared__ float xs[KC*128];
    __shared__ float wt[KC*128];
    int tid = threadIdx.x;
    int m0g = blockIdx.x * 128;
    // one-time staging of ax tile, W1, b1
    if (tid < 128) {
        b1s[tid] = b1[tid];
        #pragma unroll
        for (int f = 0; f < FIN; ++f) w1s[f][tid] = W1[tid*FIN + f];
    } else {
        int r2 = tid - 128;
        #pragma unroll
        for (int f = 0; f < FIN; ++f) axs[f][r2] = ax[(size_t)(m0g + r2)*FIN + f];
    }
    int tx = tid & 15, ty = tid >> 4;
    int m0 = ty*8;
    int j0 = tx*4;
    int r  = tid >> 1;                  // staging row 0..127
    int kq = (tid & 1) * 16;            // staging k sub-chunk
    float a[8][8];
    #pragma unroll
    for (int i = 0; i < 8; ++i)
        #pragma unroll
        for (int j = 0; j < 8; ++j) a[i][j] = 0.f;
    __syncthreads();
    float axr[FIN];
    #pragma unroll
    for (int f = 0; f < FIN; ++f) axr[f] = axs[f][r];

    for (int kh = 0; kh < 128; kh += KC) {
        float4 wv[4];
        #pragma unroll
        for (int c = 0; c < 4; ++c)
            wv[c] = *(const float4*)&W2[(size_t)r*128 + kh + kq + 4*c];
        // compute this thread's 16 H1 values: k1 = kh+kq+kk
        float hv[16];
        #pragma unroll
        for (int kk = 0; kk < 16; ++kk) {
            int k1 = kh + kq + kk;
            float sv = b1s[k1];
            #pragma unroll
            for (int f = 0; f < FIN; ++f) sv += axr[f]*w1s[f][k1];
            hv[kk] = fmaxf(sv, 0.0f);
        }
        __syncthreads();               // protect prev iter's reads
        #pragma unroll
        for (int kk = 0; kk < 16; ++kk) xs[(kq+kk)*128 + r] = hv[kk];
        #pragma unroll
        for (int c = 0; c < 4; ++c) {
            wt[(kq+4*c+0)*128 + r] = wv[c].x;
            wt[(kq+4*c+1)*128 + r] = wv[c].y;
            wt[(kq+4*c+2)*128 + r] = wv[c].z;
            wt[(kq+4*c+3)*128 + r] = wv[c].w;
        }
        __syncthreads();
        for (int k = 0; k < KC; ++k) {
            float4 xa = *(const float4*)&xs[k*128 + m0];
            float4 xb = *(const float4*)&xs[k*128 + m0 + 4];
            float4 wa = *(const float4*)&wt[k*128 + j0];
            float4 wb = *(const float4*)&wt[k*128 + j0 + 64];
            float xr[8] = {xa.x,xa.y,xa.z,xa.w,xb.x,xb.y,xb.z,xb.w};
            float wr[8] = {wa.x,wa.y,wa.z,wa.w,wb.x,wb.y,wb.z,wb.w};
            #pragma unroll
            for (int i = 0; i < 8; ++i)
                #pragma unroll
                for (int j = 0; j < 8; ++j)
                    a[i][j] += xr[i]*wr[j];
        }
    }
    #pragma unroll
    for (int i = 0; i < 8; ++i) {
        int n = m0g + m0 + i;
        float dv = dinv[n];
        float4 v0 = make_float4(a[i][0]*dv, a[i][1]*dv, a[i][2]*dv, a[i][3]*dv);
        float4 v1 = make_float4(a[i][4]*dv, a[i][5]*dv, a[i][6]*dv, a[i][7]*dv);
        *(float4*)&hs[(size_t)n*HID + j0]      = v0;
        *(float4*)&hs[(size_t)n*HID + 64 + j0] = v1;
    }
}

// layer-2 gather agg over a 64-feature half; per-graph half-slab 2.56MB fits XCD L2
__global__ __launch_bounds__(256) void k_agg2(
        const int* __restrict__ rowStart, const int* __restrict__ csrSrc,
        const float* __restrict__ hs, const float* __restrict__ dinv,
        const float* __restrict__ bias, float* __restrict__ out, int half) {
    int g = blockIdx.x;
    int graph = g & 7;
    int i = g >> 3;                         // 0..1249
    int n = graph*NN + i*8 + (threadIdx.x >> 5);
    int lane = threadIdx.x & 31;
    int col = half*32 + lane;               // float2 column
    const float2* hp = (const float2*)hs;
    float2 acc = hp[(size_t)n*64 + col];    // self-loop message
    int beg = rowStart[n], end = rowStart[n+1];
    for (int e = beg; e < end; e += 32) {
        int m = end - e; if (m > 32) m = 32;
        int s = (lane < m) ? csrSrc[e + lane] : 0;
        for (int j = 0; j < m; ++j) {
            int sj = __shfl(s, j, 32);
            float2 v = hp[(size_t)sj*64 + col];
            acc.x += v.x; acc.y += v.y;
        }
    }
    float dv = dinv[n];
    float2 bb = ((const float2*)bias)[col];
    float2 o;
    o.x = fmaxf(acc.x*dv + bb.x, 0.0f);
    o.y = fmaxf(acc.y*dv + bb.y, 0.0f);
    ((float2*)out)[(size_t)n*64 + col] = o;
}

// MLP1: block per (batch, 16-output group); 16 lanes per output, shuffle-reduce.
__global__ __launch_bounds__(256) void k_mlp1(
        const float* __restrict__ x, const int* __restrict__ avail,
        const int* __restrict__ pos, const float* __restrict__ actions,
        const float* __restrict__ steps,
        const float* __restrict__ Wp1, const float* __restrict__ bp1,
        float* __restrict__ hm) {
    int b  = blockIdx.x >> 4;
    int jg = blockIdx.x & 15;
    int t  = threadIdx.x;
    __shared__ float c[PROJ_IN];
    __shared__ int p[5];
    if (t < 4) p[t] = avail[b*4 + t] + b*NN;
    if (t == 4) p[4] = pos[b] + b*NN;
    __syncthreads();
    for (int i = t; i < 5*HID; i += 256)
        c[i] = x[(size_t)p[i >> 7]*HID + (i & 127)];
    if (t < ALAST) c[5*HID + t] = actions[b*ALAST + t];
    if (t == ALAST) c[5*HID + ALAST] = steps[b];
    __syncthreads();
    int o = t >> 4, sub = t & 15;
    int j = jg*16 + o;
    const float* wr = Wp1 + (size_t)j*PROJ_IN;
    float s = 0.f;
    for (int k = sub; k < PROJ_IN; k += 16) s += c[k]*wr[k];
    #pragma unroll
    for (int d = 8; d; d >>= 1) s += __shfl_down(s, d, 16);
    if (sub == 0) hm[b*EMB + j] = fmaxf(s + bp1[j], 0.f);
}

// MLP2: block per (batch, 16-output group); 16 lanes per output, shuffle-reduce.
__global__ __launch_bounds__(256) void k_mlp2(
        const float* __restrict__ hm, const float* __restrict__ Wp2,
        const float* __restrict__ bp2, float* __restrict__ out) {
    int b  = blockIdx.x >> 4;
    int jg = blockIdx.x & 15;
    int t  = threadIdx.x;
    __shared__ float c[EMB];
    if (t < EMB) c[t] = hm[b*EMB + t];
    __syncthreads();
    int o = t >> 4, sub = t & 15;
    int j = jg*16 + o;
    const float* wr = Wp2 + (size_t)j*EMB;
    float s = 0.f;
    for (int k = sub; k < EMB; k += 16) s += c[k]*wr[k];
    #pragma unroll
    for (int d = 8; d; d >>= 1) s += __shfl_down(s, d, 16);
    if (sub == 0) out[b*EMB + j] = s + bp2[j];
}

extern "C" void kernel_launch(void* const* d_in, const int* in_sizes, int n_in,
                              void* d_out, int out_size, void* d_ws, size_t ws_size,
                              hipStream_t stream) {
    const float* graph_x = (const float*)d_in[0];
    const int*   edges   = (const int*)d_in[1];
    const int*   pos     = (const int*)d_in[2];
    const int*   avail   = (const int*)d_in[3];
    const float* actions = (const float*)d_in[4];
    const float* steps   = (const float*)d_in[5];
    const float* W1  = (const float*)d_in[6];
    const float* b1  = (const float*)d_in[7];
    const float* W2  = (const float*)d_in[8];
    const float* b2  = (const float*)d_in[9];
    const float* Wp1 = (const float*)d_in[10];
    const float* bp1 = (const float*)d_in[11];
    const float* Wp2 = (const float*)d_in[12];
    const float* bp2 = (const float*)d_in[13];
    float* out = (float*)d_out;

    char* ws = (char*)d_ws;
    size_t off = 0;
    #define ALLOC(ptrname, type, nelem) \
        type* ptrname = (type*)(ws + off); off = (off + (size_t)(nelem)*sizeof(type) + 255) & ~(size_t)255;
    ALLOC(cnt,      int,   NNODES)
    ALLOC(rowStart, int,   NNODES+1)
    ALLOC(bsum,     int,   512)
    ALLOC(csrSrc,   int,   NEDGE)
    ALLOC(dinv,     float, NNODES)
    ALLOC(xs5,      float, (size_t)NNODES*FIN)   // SoA prescaled input
    ALLOC(ax,       float, (size_t)NNODES*FIN)   // aggregated 5-dim
    ALLOC(bufA,     float, (size_t)NNODES*HID)   // hs (layer-2 staging)
    ALLOC(bufC,     float, (size_t)NNODES*HID)   // layer-2 output
    ALLOC(hm,       float, (size_t)NB*EMB)
    #undef ALLOC

    // CSR build: node-range ownership, LDS histograms/cursors
    k_hist2<<<NB*NSLICE, 256, 0, stream>>>(edges, cnt);
    k_scan1<<<NBLK, 256, 0, stream>>>(cnt, rowStart, bsum);
    k_scan2<<<1, 512, 0, stream>>>(bsum);
    k_scan3<<<NBLK, 256, 0, stream>>>(rowStart, bsum, cnt, dinv, graph_x, xs5);
    k_fill2<<<NB*NSLICE, 256, 0, stream>>>(edges, rowStart, csrSrc);

    // layer 1 aggregation on 5-dim raw features
    k_agg5<<<8*((NN+255)/256), 256, 0, stream>>>(rowStart, csrSrc, xs5, dinv, ax);

    // fused layer-1 dense + layer-2 dense
    k_h12<<<NNODES/128, 256, 0, stream>>>(ax, W1, b1, W2, dinv, bufA);

    // layer-2 aggregation per 64-feature half
    k_agg2<<<NNODES/8, 256, 0, stream>>>(rowStart, csrSrc, bufA, dinv, b2, bufC, 0);
    k_agg2<<<NNODES/8, 256, 0, stream>>>(rowStart, csrSrc, bufA, dinv, b2, bufC, 1);

    // head
    k_mlp1<<<NB*16, 256, 0, stream>>>(bufC, avail, pos, actions, steps, Wp1, bp1, hm);
    k_mlp2<<<NB*16, 256, 0, stream>>>(hm, Wp2, bp2, out);
}

// Round 7
// 322.967 us; speedup vs baseline: 1.3332x; 1.3332x over previous
//
#include <hip/hip_runtime.h>

#define NB 8
#define NN 10000
#define NE 160000
#define NNODES (NB*NN)          // 80000
#define NEDGE (NB*NE)           // 1280000
#define FIN 5
#define HID 128
#define EMB 256
#define ALAST 10
#define PROJ_IN (HID*5 + ALAST + 1)  // 651
#define NBLK ((NNODES+255)/256)      // 313
#define ECHUNK (NE/256)              // 625 blocks per graph

// count in-degree; record each edge's rank within its dst segment.
// XCD-pinned: graph = blockIdx%8, so graph g's cnt lines live on one XCD's L2.
__global__ void k_hist(const int* __restrict__ edges, int* __restrict__ cnt,
                       int* __restrict__ rank) {
    int g = blockIdx.x & 7;
    int el = (blockIdx.x >> 3)*256 + threadIdx.x;   // 0..NE-1
    int d = edges[(size_t)g*2*NE + NE + el];
    rank[(size_t)g*NE + el] = atomicAdd(&cnt[g*NN + d], 1);
}

__global__ void k_scan1(const int* __restrict__ cnt, int* __restrict__ rowStart,
                        int* __restrict__ bsum) {
    __shared__ int sh[256];
    int tid = threadIdx.x;
    int i = blockIdx.x*256 + tid;
    int v = (i < NNODES) ? cnt[i] : 0;
    sh[tid] = v;
    __syncthreads();
    for (int off = 1; off < 256; off <<= 1) {
        int t = (tid >= off) ? sh[tid - off] : 0;
        __syncthreads();
        sh[tid] += t;
        __syncthreads();
    }
    if (i < NNODES) rowStart[i] = sh[tid] - v;          // exclusive
    if (tid == 255) bsum[blockIdx.x] = sh[255];
}

__global__ void k_scan2(int* bsum) {
    __shared__ int sh[512];
    int tid = threadIdx.x;
    int v = (tid < NBLK) ? bsum[tid] : 0;
    sh[tid] = v;
    __syncthreads();
    for (int off = 1; off < 512; off <<= 1) {
        int t = (tid >= off) ? sh[tid - off] : 0;
        __syncthreads();
        sh[tid] += t;
        __syncthreads();
    }
    if (tid < NBLK) bsum[tid] = sh[tid] - v;            // exclusive
}

// add block offsets; compute dinv; prescale 5-dim features into SoA xs5
__global__ void k_scan3(int* __restrict__ rowStart, const int* __restrict__ bsum,
                        const int* __restrict__ cnt, float* __restrict__ dinv,
                        const float* __restrict__ x, float* __restrict__ xs5) {
    int i = blockIdx.x*256 + threadIdx.x;
    if (i < NNODES) {
        rowStart[i] = rowStart[i] + bsum[blockIdx.x];
        float dv = rsqrtf(1.0f + (float)cnt[i]);        // +1 = self loop
        dinv[i] = dv;
        #pragma unroll
        for (int f = 0; f < FIN; ++f)
            xs5[f*NNODES + i] = x[(size_t)i*FIN + f] * dv;
    }
    if (i == 0) rowStart[NNODES] = NEDGE;
}

// no atomics: position = rowStart[d] + rank[e]. XCD-pinned like k_hist so the
// scattered csrSrc stores hit one XCD's L2 (graph segment = 640KB < 4MB).
__global__ void k_fill(const int* __restrict__ edges, const int* __restrict__ rowStart,
                       const int* __restrict__ rank, int* __restrict__ csrSrc) {
    int g = blockIdx.x & 7;
    int el = (blockIdx.x >> 3)*256 + threadIdx.x;
    int s = edges[(size_t)g*2*NE + el];
    int d = edges[(size_t)g*2*NE + NE + el];
    csrSrc[rowStart[g*NN + d] + rank[(size_t)g*NE + el]] = g*NN + s;
}

// layer-1 aggregation on the 5 raw features (agg commutes with dense transform).
__global__ __launch_bounds__(256) void k_agg5(
        const int* __restrict__ rowStart, const int* __restrict__ csrSrc,
        const float* __restrict__ xs5, const float* __restrict__ dinv,
        float* __restrict__ ax) {
    int g = blockIdx.x;
    int graph = g & 7;
    int nl = (g >> 3)*256 + threadIdx.x;
    if (nl >= NN) return;
    int n = graph*NN + nl;
    float a0 = xs5[0*NNODES + n], a1 = xs5[1*NNODES + n], a2 = xs5[2*NNODES + n],
          a3 = xs5[3*NNODES + n], a4 = xs5[4*NNODES + n];
    int beg = rowStart[n], end = rowStart[n+1];
    for (int e = beg; e < end; ++e) {
        int s = csrSrc[e];
        a0 += xs5[0*NNODES + s];
        a1 += xs5[1*NNODES + s];
        a2 += xs5[2*NNODES + s];
        a3 += xs5[3*NNODES + s];
        a4 += xs5[4*NNODES + s];
    }
    float dv = dinv[n];
    ax[(size_t)n*FIN + 0] = a0*dv;
    ax[(size_t)n*FIN + 1] = a1*dv;
    ax[(size_t)n*FIN + 2] = a2*dv;
    ax[(size_t)n*FIN + 3] = a3*dv;
    ax[(size_t)n*FIN + 4] = a4*dv;
}

// Fused layer-1 dense + layer-2 dense:
// H1 = relu(ax @ W1^T + b1) computed on the fly per tile (never materialized),
// hs = (H1 @ W2^T) * dinv.  128x128 tile, 8x8 per thread.
#define KC 32
__global__ __launch_bounds__(256) void k_h12(
        const float* __restrict__ ax, const float* __restrict__ W1,
        const float* __restrict__ b1, const float* __restrict__ W2,
        const float* __restrict__ dinv, float* __restrict__ hs) {
    __shared__ float axs[FIN][128];
    __shared__ float w1s[FIN][128];
    __shared__ float b1s[128];
    __shared__ float xs[KC*128];
    __shared__ float wt[KC*128];
    int tid = threadIdx.x;
    int m0g = blockIdx.x * 128;
    if (tid < 128) {
        b1s[tid] = b1[tid];
        #pragma unroll
        for (int f = 0; f < FIN; ++f) w1s[f][tid] = W1[tid*FIN + f];
    } else {
        int r2 = tid - 128;
        #pragma unroll
        for (int f = 0; f < FIN; ++f) axs[f][r2] = ax[(size_t)(m0g + r2)*FIN + f];
    }
    int tx = tid & 15, ty = tid >> 4;
    int m0 = ty*8;
    int j0 = tx*4;
    int r  = tid >> 1;                  // staging row 0..127
    int kq = (tid & 1) * 16;            // staging k sub-chunk
    float a[8][8];
    #pragma unroll
    for (int i = 0; i < 8; ++i)
        #pragma unroll
        for (int j = 0; j < 8; ++j) a[i][j] = 0.f;
    __syncthreads();
    float axr[FIN];
    #pragma unroll
    for (int f = 0; f < FIN; ++f) axr[f] = axs[f][r];

    for (int kh = 0; kh < 128; kh += KC) {
        float4 wv[4];
        #pragma unroll
        for (int c = 0; c < 4; ++c)
            wv[c] = *(const float4*)&W2[(size_t)r*128 + kh + kq + 4*c];
        float hv[16];
        #pragma unroll
        for (int kk = 0; kk < 16; ++kk) {
            int k1 = kh + kq + kk;
            float sv = b1s[k1];
            #pragma unroll
            for (int f = 0; f < FIN; ++f) sv += axr[f]*w1s[f][k1];
            hv[kk] = fmaxf(sv, 0.0f);
        }
        __syncthreads();               // protect prev iter's reads
        #pragma unroll
        for (int kk = 0; kk < 16; ++kk) xs[(kq+kk)*128 + r] = hv[kk];
        #pragma unroll
        for (int c = 0; c < 4; ++c) {
            wt[(kq+4*c+0)*128 + r] = wv[c].x;
            wt[(kq+4*c+1)*128 + r] = wv[c].y;
            wt[(kq+4*c+2)*128 + r] = wv[c].z;
            wt[(kq+4*c+3)*128 + r] = wv[c].w;
        }
        __syncthreads();
        for (int k = 0; k < KC; ++k) {
            float4 xa = *(const float4*)&xs[k*128 + m0];
            float4 xb = *(const float4*)&xs[k*128 + m0 + 4];
            float4 wa = *(const float4*)&wt[k*128 + j0];
            float4 wb = *(const float4*)&wt[k*128 + j0 + 64];
            float xr[8] = {xa.x,xa.y,xa.z,xa.w,xb.x,xb.y,xb.z,xb.w};
            float wr[8] = {wa.x,wa.y,wa.z,wa.w,wb.x,wb.y,wb.z,wb.w};
            #pragma unroll
            for (int i = 0; i < 8; ++i)
                #pragma unroll
                for (int j = 0; j < 8; ++j)
                    a[i][j] += xr[i]*wr[j];
        }
    }
    #pragma unroll
    for (int i = 0; i < 8; ++i) {
        int n = m0g + m0 + i;
        float dv = dinv[n];
        float4 v0 = make_float4(a[i][0]*dv, a[i][1]*dv, a[i][2]*dv, a[i][3]*dv);
        float4 v1 = make_float4(a[i][4]*dv, a[i][5]*dv, a[i][6]*dv, a[i][7]*dv);
        *(float4*)&hs[(size_t)n*HID + j0]      = v0;
        *(float4*)&hs[(size_t)n*HID + 64 + j0] = v1;
    }
}

// layer-2 gather agg over a 64-feature half; per-graph half-slab 2.56MB fits XCD L2
__global__ __launch_bounds__(256) void k_agg2(
        const int* __restrict__ rowStart, const int* __restrict__ csrSrc,
        const float* __restrict__ hs, const float* __restrict__ dinv,
        const float* __restrict__ bias, float* __restrict__ out, int half) {
    int g = blockIdx.x;
    int graph = g & 7;
    int i = g >> 3;                         // 0..1249
    int n = graph*NN + i*8 + (threadIdx.x >> 5);
    int lane = threadIdx.x & 31;
    int col = half*32 + lane;               // float2 column
    const float2* hp = (const float2*)hs;
    float2 acc = hp[(size_t)n*64 + col];    // self-loop message
    int beg = rowStart[n], end = rowStart[n+1];
    for (int e = beg; e < end; e += 32) {
        int m = end - e; if (m > 32) m = 32;
        int s = (lane < m) ? csrSrc[e + lane] : 0;
        for (int j = 0; j < m; ++j) {
            int sj = __shfl(s, j, 32);
            float2 v = hp[(size_t)sj*64 + col];
            acc.x += v.x; acc.y += v.y;
        }
    }
    float dv = dinv[n];
    float2 bb = ((const float2*)bias)[col];
    float2 o;
    o.x = fmaxf(acc.x*dv + bb.x, 0.0f);
    o.y = fmaxf(acc.y*dv + bb.y, 0.0f);
    ((float2*)out)[(size_t)n*64 + col] = o;
}

// MLP1: block per (batch, 16-output group); 16 lanes per output, shuffle-reduce.
__global__ __launch_bounds__(256) void k_mlp1(
        const float* __restrict__ x, const int* __restrict__ avail,
        const int* __restrict__ pos, const float* __restrict__ actions,
        const float* __restrict__ steps,
        const float* __restrict__ Wp1, const float* __restrict__ bp1,
        float* __restrict__ hm) {
    int b  = blockIdx.x >> 4;
    int jg = blockIdx.x & 15;
    int t  = threadIdx.x;
    __shared__ float c[PROJ_IN];
    __shared__ int p[5];
    if (t < 4) p[t] = avail[b*4 + t] + b*NN;
    if (t == 4) p[4] = pos[b] + b*NN;
    __syncthreads();
    for (int i = t; i < 5*HID; i += 256)
        c[i] = x[(size_t)p[i >> 7]*HID + (i & 127)];
    if (t < ALAST) c[5*HID + t] = actions[b*ALAST + t];
    if (t == ALAST) c[5*HID + ALAST] = steps[b];
    __syncthreads();
    int o = t >> 4, sub = t & 15;
    int j = jg*16 + o;
    const float* wr = Wp1 + (size_t)j*PROJ_IN;
    float s = 0.f;
    for (int k = sub; k < PROJ_IN; k += 16) s += c[k]*wr[k];
    #pragma unroll
    for (int d = 8; d; d >>= 1) s += __shfl_down(s, d, 16);
    if (sub == 0) hm[b*EMB + j] = fmaxf(s + bp1[j], 0.f);
}

// MLP2: block per (batch, 16-output group); 16 lanes per output, shuffle-reduce.
__global__ __launch_bounds__(256) void k_mlp2(
        const float* __restrict__ hm, const float* __restrict__ Wp2,
        const float* __restrict__ bp2, float* __restrict__ out) {
    int b  = blockIdx.x >> 4;
    int jg = blockIdx.x & 15;
    int t  = threadIdx.x;
    __shared__ float c[EMB];
    if (t < EMB) c[t] = hm[b*EMB + t];
    __syncthreads();
    int o = t >> 4, sub = t & 15;
    int j = jg*16 + o;
    const float* wr = Wp2 + (size_t)j*EMB;
    float s = 0.f;
    for (int k = sub; k < EMB; k += 16) s += c[k]*wr[k];
    #pragma unroll
    for (int d = 8; d; d >>= 1) s += __shfl_down(s, d, 16);
    if (sub == 0) out[b*EMB + j] = s + bp2[j];
}

extern "C" void kernel_launch(void* const* d_in, const int* in_sizes, int n_in,
                              void* d_out, int out_size, void* d_ws, size_t ws_size,
                              hipStream_t stream) {
    const float* graph_x = (const float*)d_in[0];
    const int*   edges   = (const int*)d_in[1];
    const int*   pos     = (const int*)d_in[2];
    const int*   avail   = (const int*)d_in[3];
    const float* actions = (const float*)d_in[4];
    const float* steps   = (const float*)d_in[5];
    const float* W1  = (const float*)d_in[6];
    const float* b1  = (const float*)d_in[7];
    const float* W2  = (const float*)d_in[8];
    const float* b2  = (const float*)d_in[9];
    const float* Wp1 = (const float*)d_in[10];
    const float* bp1 = (const float*)d_in[11];
    const float* Wp2 = (const float*)d_in[12];
    const float* bp2 = (const float*)d_in[13];
    float* out = (float*)d_out;

    char* ws = (char*)d_ws;
    size_t off = 0;
    #define ALLOC(ptrname, type, nelem) \
        type* ptrname = (type*)(ws + off); off = (off + (size_t)(nelem)*sizeof(type) + 255) & ~(size_t)255;
    ALLOC(cnt,      int,   NNODES)
    ALLOC(rowStart, int,   NNODES+1)
    ALLOC(bsum,     int,   512)
    ALLOC(rank,     int,   NEDGE)
    ALLOC(csrSrc,   int,   NEDGE)
    ALLOC(dinv,     float, NNODES)
    ALLOC(xs5,      float, (size_t)NNODES*FIN)   // SoA prescaled input
    ALLOC(ax,       float, (size_t)NNODES*FIN)   // aggregated 5-dim
    ALLOC(bufA,     float, (size_t)NNODES*HID)   // hs (layer-2 staging)
    ALLOC(bufC,     float, (size_t)NNODES*HID)   // layer-2 output
    ALLOC(hm,       float, (size_t)NB*EMB)
    #undef ALLOC

    hipMemsetAsync(cnt, 0, (size_t)NNODES*4, stream);
    k_hist<<<NB*ECHUNK, 256, 0, stream>>>(edges, cnt, rank);
    k_scan1<<<NBLK, 256, 0, stream>>>(cnt, rowStart, bsum);
    k_scan2<<<1, 512, 0, stream>>>(bsum);
    k_scan3<<<NBLK, 256, 0, stream>>>(rowStart, bsum, cnt, dinv, graph_x, xs5);
    k_fill<<<NB*ECHUNK, 256, 0, stream>>>(edges, rowStart, rank, csrSrc);

    // layer 1 aggregation on 5-dim raw features
    k_agg5<<<8*((NN+255)/256), 256, 0, stream>>>(rowStart, csrSrc, xs5, dinv, ax);

    // fused layer-1 dense + layer-2 dense
    k_h12<<<NNODES/128, 256, 0, stream>>>(ax, W1, b1, W2, dinv, bufA);

    // layer-2 aggregation per 64-feature half
    k_agg2<<<NNODES/8, 256, 0, stream>>>(rowStart, csrSrc, bufA, dinv, b2, bufC, 0);
    k_agg2<<<NNODES/8, 256, 0, stream>>>(rowStart, csrSrc, bufA, dinv, b2, bufC, 1);

    // head
    k_mlp1<<<NB*16, 256, 0, stream>>>(bufC, avail, pos, actions, steps, Wp1, bp1, hm);
    k_mlp2<<<NB*16, 256, 0, stream>>>(hm, Wp2, bp2, out);
}

// Round 8
// 287.896 us; speedup vs baseline: 1.4956x; 1.1218x over previous
//
#include <hip/hip_runtime.h>

#define NB 8
#define NN 10000
#define NE 160000
#define NNODES (NB*NN)          // 80000
#define NEDGE (NB*NE)           // 1280000
#define FIN 5
#define HID 128
#define EMB 256
#define ALAST 10
#define PROJ_IN (HID*5 + ALAST + 1)  // 651
#define NBLK ((NNODES+255)/256)      // 313
#define GB 32                        // blocks per graph for CSR build
#define EPB (NE/GB)                  // 5000 edges per block

// ---- CSR build, no global atomics ----
// Per-block LDS histogram of the full 10000-bin node range; rank via LDS atomic.
__global__ __launch_bounds__(256) void k_histL(const int* __restrict__ edges,
                                               int* __restrict__ hist,
                                               int* __restrict__ rankL) {
    int g = blockIdx.x & 7;                 // XCD pin
    int b = blockIdx.x >> 3;                // 0..GB-1
    __shared__ __align__(16) int c[NN];
    int4* c4 = (int4*)c;
    for (int i = threadIdx.x; i < NN/4; i += 256) c4[i] = make_int4(0,0,0,0);
    __syncthreads();
    const int* dstp = edges + (size_t)g*2*NE + NE + b*EPB;
    int* rl = rankL + (size_t)g*NE + b*EPB;
    const int4* d4p = (const int4*)dstp;
    for (int i = threadIdx.x; i < EPB/4; i += 256) {
        int4 d4 = d4p[i];
        int e0 = 4*i;
        rl[e0+0] = atomicAdd(&c[d4.x], 1);
        rl[e0+1] = atomicAdd(&c[d4.y], 1);
        rl[e0+2] = atomicAdd(&c[d4.z], 1);
        rl[e0+3] = atomicAdd(&c[d4.w], 1);
    }
    __syncthreads();
    int4* hp = (int4*)(hist + (size_t)(g*GB + b)*NN);
    for (int i = threadIdx.x; i < NN/4; i += 256) hp[i] = c4[i];
}

// per-dst prefix across the GB block-hists; emit cnt, leave block offsets in hist
__global__ void k_scanB(int* __restrict__ hist, int* __restrict__ cnt) {
    int n = blockIdx.x*256 + threadIdx.x;
    if (n >= NNODES) return;
    int g = n / NN, dl = n - g*NN;
    int* hbase = hist + (size_t)g*GB*NN + dl;
    int run = 0;
    #pragma unroll
    for (int b = 0; b < GB; ++b) {
        int v = hbase[(size_t)b*NN];
        hbase[(size_t)b*NN] = run;          // exclusive within-dst offset
        run += v;
    }
    cnt[n] = run;
}

__global__ void k_scan1(const int* __restrict__ cnt, int* __restrict__ rowStart,
                        int* __restrict__ bsum) {
    __shared__ int sh[256];
    int tid = threadIdx.x;
    int i = blockIdx.x*256 + tid;
    int v = (i < NNODES) ? cnt[i] : 0;
    sh[tid] = v;
    __syncthreads();
    for (int off = 1; off < 256; off <<= 1) {
        int t = (tid >= off) ? sh[tid - off] : 0;
        __syncthreads();
        sh[tid] += t;
        __syncthreads();
    }
    if (i < NNODES) rowStart[i] = sh[tid] - v;          // exclusive
    if (tid == 255) bsum[blockIdx.x] = sh[255];
}

__global__ void k_scan2(int* bsum) {
    __shared__ int sh[512];
    int tid = threadIdx.x;
    int v = (tid < NBLK) ? bsum[tid] : 0;
    sh[tid] = v;
    __syncthreads();
    for (int off = 1; off < 512; off <<= 1) {
        int t = (tid >= off) ? sh[tid - off] : 0;
        __syncthreads();
        sh[tid] += t;
        __syncthreads();
    }
    if (tid < NBLK) bsum[tid] = sh[tid] - v;            // exclusive
}

// add block offsets; compute dinv; prescale 5-dim features into SoA xs5
__global__ void k_scan3(int* __restrict__ rowStart, const int* __restrict__ bsum,
                        const int* __restrict__ cnt, float* __restrict__ dinv,
                        const float* __restrict__ x, float* __restrict__ xs5) {
    int i = blockIdx.x*256 + threadIdx.x;
    if (i < NNODES) {
        rowStart[i] = rowStart[i] + bsum[blockIdx.x];
        float dv = rsqrtf(1.0f + (float)cnt[i]);        // +1 = self loop
        dinv[i] = dv;
        #pragma unroll
        for (int f = 0; f < FIN; ++f)
            xs5[f*NNODES + i] = x[(size_t)i*FIN + f] * dv;
    }
    if (i == 0) rowStart[NNODES] = NEDGE;
}

// p = rowStart[dst] + blockOffset[b][dst] + rank_local[e]; plain stores only.
__global__ __launch_bounds__(256) void k_fillL(const int* __restrict__ edges,
                                               const int* __restrict__ rowStart,
                                               const int* __restrict__ hist,
                                               const int* __restrict__ rankL,
                                               int* __restrict__ csrSrc) {
    int g = blockIdx.x & 7;
    int b = blockIdx.x >> 3;
    const int* base = edges + (size_t)g*2*NE;
    const int4* s4p = (const int4*)(base + b*EPB);
    const int4* d4p = (const int4*)(base + NE + b*EPB);
    const int4* r4p = (const int4*)(rankL + (size_t)g*NE + b*EPB);
    const int* rs = rowStart + g*NN;
    const int* ho = hist + (size_t)(g*GB + b)*NN;
    int gofs = g*NN;
    for (int i = threadIdx.x; i < EPB/4; i += 256) {
        int4 s4 = s4p[i];
        int4 d4 = d4p[i];
        int4 r4 = r4p[i];
        csrSrc[rs[d4.x] + ho[d4.x] + r4.x] = s4.x + gofs;
        csrSrc[rs[d4.y] + ho[d4.y] + r4.y] = s4.y + gofs;
        csrSrc[rs[d4.z] + ho[d4.z] + r4.z] = s4.z + gofs;
        csrSrc[rs[d4.w] + ho[d4.w] + r4.w] = s4.w + gofs;
    }
}

// layer-1 aggregation on the 5 raw features (agg commutes with dense transform).
__global__ __launch_bounds__(256) void k_agg5(
        const int* __restrict__ rowStart, const int* __restrict__ csrSrc,
        const float* __restrict__ xs5, const float* __restrict__ dinv,
        float* __restrict__ ax) {
    int g = blockIdx.x;
    int graph = g & 7;
    int nl = (g >> 3)*256 + threadIdx.x;
    if (nl >= NN) return;
    int n = graph*NN + nl;
    float a0 = xs5[0*NNODES + n], a1 = xs5[1*NNODES + n], a2 = xs5[2*NNODES + n],
          a3 = xs5[3*NNODES + n], a4 = xs5[4*NNODES + n];
    int beg = rowStart[n], end = rowStart[n+1];
    for (int e = beg; e < end; ++e) {
        int s = csrSrc[e];
        a0 += xs5[0*NNODES + s];
        a1 += xs5[1*NNODES + s];
        a2 += xs5[2*NNODES + s];
        a3 += xs5[3*NNODES + s];
        a4 += xs5[4*NNODES + s];
    }
    float dv = dinv[n];
    ax[(size_t)n*FIN + 0] = a0*dv;
    ax[(size_t)n*FIN + 1] = a1*dv;
    ax[(size_t)n*FIN + 2] = a2*dv;
    ax[(size_t)n*FIN + 3] = a3*dv;
    ax[(size_t)n*FIN + 4] = a4*dv;
}

// Fused layer-1 dense + layer-2 dense:
// H1 = relu(ax @ W1^T + b1) computed on the fly per tile (never materialized),
// hs = (H1 @ W2^T) * dinv.  128x128 tile, 8x8 per thread.
#define KC 32
__global__ __launch_bounds__(256) void k_h12(
        const float* __restrict__ ax, const float* __restrict__ W1,
        const float* __restrict__ b1, const float* __restrict__ W2,
        const float* __restrict__ dinv, float* __restrict__ hs) {
    __shared__ float axs[FIN][128];
    __shared__ float w1s[FIN][128];
    __shared__ float b1s[128];
    __shared__ float xs[KC*128];
    __shared__ float wt[KC*128];
    int tid = threadIdx.x;
    int m0g = blockIdx.x * 128;
    if (tid < 128) {
        b1s[tid] = b1[tid];
        #pragma unroll
        for (int f = 0; f < FIN; ++f) w1s[f][tid] = W1[tid*FIN + f];
    } else {
        int r2 = tid - 128;
        #pragma unroll
        for (int f = 0; f < FIN; ++f) axs[f][r2] = ax[(size_t)(m0g + r2)*FIN + f];
    }
    int tx = tid & 15, ty = tid >> 4;
    int m0 = ty*8;
    int j0 = tx*4;
    int r  = tid >> 1;                  // staging row 0..127
    int kq = (tid & 1) * 16;            // staging k sub-chunk
    float a[8][8];
    #pragma unroll
    for (int i = 0; i < 8; ++i)
        #pragma unroll
        for (int j = 0; j < 8; ++j) a[i][j] = 0.f;
    __syncthreads();
    float axr[FIN];
    #pragma unroll
    for (int f = 0; f < FIN; ++f) axr[f] = axs[f][r];

    for (int kh = 0; kh < 128; kh += KC) {
        float4 wv[4];
        #pragma unroll
        for (int c = 0; c < 4; ++c)
            wv[c] = *(const float4*)&W2[(size_t)r*128 + kh + kq + 4*c];
        float hv[16];
        #pragma unroll
        for (int kk = 0; kk < 16; ++kk) {
            int k1 = kh + kq + kk;
            float sv = b1s[k1];
            #pragma unroll
            for (int f = 0; f < FIN; ++f) sv += axr[f]*w1s[f][k1];
            hv[kk] = fmaxf(sv, 0.0f);
        }
        __syncthreads();               // protect prev iter's reads
        #pragma unroll
        for (int kk = 0; kk < 16; ++kk) xs[(kq+kk)*128 + r] = hv[kk];
        #pragma unroll
        for (int c = 0; c < 4; ++c) {
            wt[(kq+4*c+0)*128 + r] = wv[c].x;
            wt[(kq+4*c+1)*128 + r] = wv[c].y;
            wt[(kq+4*c+2)*128 + r] = wv[c].z;
            wt[(kq+4*c+3)*128 + r] = wv[c].w;
        }
        __syncthreads();
        for (int k = 0; k < KC; ++k) {
            float4 xa = *(const float4*)&xs[k*128 + m0];
            float4 xb = *(const float4*)&xs[k*128 + m0 + 4];
            float4 wa = *(const float4*)&wt[k*128 + j0];
            float4 wb = *(const float4*)&wt[k*128 + j0 + 64];
            float xr[8] = {xa.x,xa.y,xa.z,xa.w,xb.x,xb.y,xb.z,xb.w};
            float wr[8] = {wa.x,wa.y,wa.z,wa.w,wb.x,wb.y,wb.z,wb.w};
            #pragma unroll
            for (int i = 0; i < 8; ++i)
                #pragma unroll
                for (int j = 0; j < 8; ++j)
                    a[i][j] += xr[i]*wr[j];
        }
    }
    #pragma unroll
    for (int i = 0; i < 8; ++i) {
        int n = m0g + m0 + i;
        float dv = dinv[n];
        float4 v0 = make_float4(a[i][0]*dv, a[i][1]*dv, a[i][2]*dv, a[i][3]*dv);
        float4 v1 = make_float4(a[i][4]*dv, a[i][5]*dv, a[i][6]*dv, a[i][7]*dv);
        *(float4*)&hs[(size_t)n*HID + j0]      = v0;
        *(float4*)&hs[(size_t)n*HID + 64 + j0] = v1;
    }
}

// layer-2 gather agg over a 64-feature half; per-graph half-slab 2.56MB fits XCD L2
__global__ __launch_bounds__(256) void k_agg2(
        const int* __restrict__ rowStart, const int* __restrict__ csrSrc,
        const float* __restrict__ hs, const float* __restrict__ dinv,
        const float* __restrict__ bias, float* __restrict__ out, int half) {
    int g = blockIdx.x;
    int graph = g & 7;
    int i = g >> 3;                         // 0..1249
    int n = graph*NN + i*8 + (threadIdx.x >> 5);
    int lane = threadIdx.x & 31;
    int col = half*32 + lane;               // float2 column
    const float2* hp = (const float2*)hs;
    float2 acc = hp[(size_t)n*64 + col];    // self-loop message
    int beg = rowStart[n], end = rowStart[n+1];
    for (int e = beg; e < end; e += 32) {
        int m = end - e; if (m > 32) m = 32;
        int s = (lane < m) ? csrSrc[e + lane] : 0;
        for (int j = 0; j < m; ++j) {
            int sj = __shfl(s, j, 32);
            float2 v = hp[(size_t)sj*64 + col];
            acc.x += v.x; acc.y += v.y;
        }
    }
    float dv = dinv[n];
    float2 bb = ((const float2*)bias)[col];
    float2 o;
    o.x = fmaxf(acc.x*dv + bb.x, 0.0f);
    o.y = fmaxf(acc.y*dv + bb.y, 0.0f);
    ((float2*)out)[(size_t)n*64 + col] = o;
}

// MLP1: block per (batch, 16-output group); 16 lanes per output, shuffle-reduce.
__global__ __launch_bounds__(256) void k_mlp1(
        const float* __restrict__ x, const int* __restrict__ avail,
        const int* __restrict__ pos, const float* __restrict__ actions,
        const float* __restrict__ steps,
        const float* __restrict__ Wp1, const float* __restrict__ bp1,
        float* __restrict__ hm) {
    int b  = blockIdx.x >> 4;
    int jg = blockIdx.x & 15;
    int t  = threadIdx.x;
    __shared__ float c[PROJ_IN];
    __shared__ int p[5];
    if (t < 4) p[t] = avail[b*4 + t] + b*NN;
    if (t == 4) p[4] = pos[b] + b*NN;
    __syncthreads();
    for (int i = t; i < 5*HID; i += 256)
        c[i] = x[(size_t)p[i >> 7]*HID + (i & 127)];
    if (t < ALAST) c[5*HID + t] = actions[b*ALAST + t];
    if (t == ALAST) c[5*HID + ALAST] = steps[b];
    __syncthreads();
    int o = t >> 4, sub = t & 15;
    int j = jg*16 + o;
    const float* wr = Wp1 + (size_t)j*PROJ_IN;
    float s = 0.f;
    for (int k = sub; k < PROJ_IN; k += 16) s += c[k]*wr[k];
    #pragma unroll
    for (int d = 8; d; d >>= 1) s += __shfl_down(s, d, 16);
    if (sub == 0) hm[b*EMB + j] = fmaxf(s + bp1[j], 0.f);
}

// MLP2: block per (batch, 16-output group); 16 lanes per output, shuffle-reduce.
__global__ __launch_bounds__(256) void k_mlp2(
        const float* __restrict__ hm, const float* __restrict__ Wp2,
        const float* __restrict__ bp2, float* __restrict__ out) {
    int b  = blockIdx.x >> 4;
    int jg = blockIdx.x & 15;
    int t  = threadIdx.x;
    __shared__ float c[EMB];
    if (t < EMB) c[t] = hm[b*EMB + t];
    __syncthreads();
    int o = t >> 4, sub = t & 15;
    int j = jg*16 + o;
    const float* wr = Wp2 + (size_t)j*EMB;
    float s = 0.f;
    for (int k = sub; k < EMB; k += 16) s += c[k]*wr[k];
    #pragma unroll
    for (int d = 8; d; d >>= 1) s += __shfl_down(s, d, 16);
    if (sub == 0) out[b*EMB + j] = s + bp2[j];
}

extern "C" void kernel_launch(void* const* d_in, const int* in_sizes, int n_in,
                              void* d_out, int out_size, void* d_ws, size_t ws_size,
                              hipStream_t stream) {
    const float* graph_x = (const float*)d_in[0];
    const int*   edges   = (const int*)d_in[1];
    const int*   pos     = (const int*)d_in[2];
    const int*   avail   = (const int*)d_in[3];
    const float* actions = (const float*)d_in[4];
    const float* steps   = (const float*)d_in[5];
    const float* W1  = (const float*)d_in[6];
    const float* b1  = (const float*)d_in[7];
    const float* W2  = (const float*)d_in[8];
    const float* b2  = (const float*)d_in[9];
    const float* Wp1 = (const float*)d_in[10];
    const float* bp1 = (const float*)d_in[11];
    const float* Wp2 = (const float*)d_in[12];
    const float* bp2 = (const float*)d_in[13];
    float* out = (float*)d_out;

    char* ws = (char*)d_ws;
    size_t off = 0;
    #define ALLOC(ptrname, type, nelem) \
        type* ptrname = (type*)(ws + off); off = (off + (size_t)(nelem)*sizeof(type) + 255) & ~(size_t)255;
    ALLOC(cnt,      int,   NNODES)
    ALLOC(rowStart, int,   NNODES+1)
    ALLOC(bsum,     int,   512)
    ALLOC(hist,     int,   (size_t)NB*GB*NN)     // per-block histograms / offsets
    ALLOC(rankL,    int,   NEDGE)
    ALLOC(csrSrc,   int,   NEDGE)
    ALLOC(dinv,     float, NNODES)
    ALLOC(xs5,      float, (size_t)NNODES*FIN)   // SoA prescaled input
    ALLOC(ax,       float, (size_t)NNODES*FIN)   // aggregated 5-dim
    ALLOC(bufA,     float, (size_t)NNODES*HID)   // hs (layer-2 staging)
    ALLOC(bufC,     float, (size_t)NNODES*HID)   // layer-2 output
    ALLOC(hm,       float, (size_t)NB*EMB)
    #undef ALLOC

    // CSR build: LDS histograms, no global atomics
    k_histL<<<NB*GB, 256, 0, stream>>>(edges, hist, rankL);
    k_scanB<<<NBLK, 256, 0, stream>>>(hist, cnt);
    k_scan1<<<NBLK, 256, 0, stream>>>(cnt, rowStart, bsum);
    k_scan2<<<1, 512, 0, stream>>>(bsum);
    k_scan3<<<NBLK, 256, 0, stream>>>(rowStart, bsum, cnt, dinv, graph_x, xs5);
    k_fillL<<<NB*GB, 256, 0, stream>>>(edges, rowStart, hist, rankL, csrSrc);

    // layer 1 aggregation on 5-dim raw features
    k_agg5<<<8*((NN+255)/256), 256, 0, stream>>>(rowStart, csrSrc, xs5, dinv, ax);

    // fused layer-1 dense + layer-2 dense
    k_h12<<<NNODES/128, 256, 0, stream>>>(ax, W1, b1, W2, dinv, bufA);

    // layer-2 aggregation per 64-feature half
    k_agg2<<<NNODES/8, 256, 0, stream>>>(rowStart, csrSrc, bufA, dinv, b2, bufC, 0);
    k_agg2<<<NNODES/8, 256, 0, stream>>>(rowStart, csrSrc, bufA, dinv, b2, bufC, 1);

    // head
    k_mlp1<<<NB*16, 256, 0, stream>>>(bufC, avail, pos, actions, steps, Wp1, bp1, hm);
    k_mlp2<<<NB*16, 256, 0, stream>>>(hm, Wp2, bp2, out);
}